// Round 2
// baseline (363.683 us; speedup 1.0000x reference)
//
#include <hip/hip_runtime.h>
#include <stdint.h>

#define D_MODEL 2048
#define RANK    64
#define BATCH   16384

#define BM      32      // rows per block
#define KSTEP   64      // K staged per iteration
#define LDA     72      // padded ushort row stride (144 B) -> 2-way bank aliasing (free)

typedef unsigned short u16;
typedef __attribute__((ext_vector_type(8))) short  bf16x8;
typedef __attribute__((ext_vector_type(4))) float  f32x4;
typedef __attribute__((ext_vector_type(4))) unsigned short u16x4;

// ws layout (ushort elements):
#define WCAT_HI 0                         // [192][2048] bf16 hi of {W_dt;W_ph;W_B}
#define WCAT_LO (192*2048)                // 393216
#define WC_HI   (2*192*2048)              // 786432  [2048][64] bf16 hi of W_C
#define WC_LO   (2*192*2048 + 2048*64)    // 917504
// total 1048576 ushort = 2 MiB required in d_ws

__device__ __forceinline__ u16 f2bf(float f) {
    uint32_t u = __float_as_uint(f);
    u += 0x7fffu + ((u >> 16) & 1u);      // RNE to bf16
    return (u16)(u >> 16);
}
__device__ __forceinline__ float bf2f(u16 h) {
    return __uint_as_float(((uint32_t)h) << 16);
}

#define MFMA(a, b, c) __builtin_amdgcn_mfma_f32_16x16x32_bf16((a), (b), (c), 0, 0, 0)

// ---------------- prep: split weights into bf16 hi/lo ----------------
__global__ __launch_bounds__(256) void prep_split(
    const float* __restrict__ Wdt, const float* __restrict__ Wph,
    const float* __restrict__ WB,  const float* __restrict__ WC,
    u16* __restrict__ ws)
{
    int t = blockIdx.x * 256 + threadIdx.x;   // 131072 threads, 4 elems each
    if (t < 98304) {                          // wcat: 192*2048/4
        int i = t << 2;
        int n = i >> 11, k = i & 2047;
        const float* src = (n < 64)  ? (Wdt + n * 2048 + k)
                         : (n < 128) ? (Wph + (n - 64) * 2048 + k)
                                     : (WB  + (n - 128) * 2048 + k);
        f32x4 v = *(const f32x4*)src;
        u16x4 hi, lo;
        #pragma unroll
        for (int j = 0; j < 4; ++j) {
            hi[j] = f2bf(v[j]);
            lo[j] = f2bf(v[j] - bf2f(hi[j]));
        }
        *(u16x4*)(ws + WCAT_HI + i) = hi;
        *(u16x4*)(ws + WCAT_LO + i) = lo;
    } else {                                  // W_C: 2048*64/4
        int i = (t - 98304) << 2;
        f32x4 v = *(const f32x4*)(WC + i);
        u16x4 hi, lo;
        #pragma unroll
        for (int j = 0; j < 4; ++j) {
            hi[j] = f2bf(v[j]);
            lo[j] = f2bf(v[j] - bf2f(hi[j]));
        }
        *(u16x4*)(ws + WC_HI + i) = hi;
        *(u16x4*)(ws + WC_LO + i) = lo;
    }
}

// ---------------- fused main kernel ----------------
// block = 256 threads (4 waves), BM = 32 rows, grid = 512
// Stage 1: Y[32][192] = x_tile @ Wcat^T via bf16x3 MFMA (A from LDS, B frags from L2)
// Middle : elementwise state update, fully in-register (wave w owns rank cols [16w,16w+16))
// Stage 2: out[32][2048] = new_re @ W_C^T via bf16x3 MFMA
__global__ __launch_bounds__(256, 2) void mamba_fused(
    const float* __restrict__ x,
    const float* __restrict__ state_re, const float* __restrict__ state_im,
    const float* __restrict__ b_dt, const float* __restrict__ b_ph,
    const float* __restrict__ A_real, const float* __restrict__ A_imag,
    const u16* __restrict__ ws,
    float* __restrict__ dout)
{
    __shared__ __align__(16) u16 xa_hi[BM * LDA];
    __shared__ __align__(16) u16 xa_lo[BM * LDA];
    __shared__ __align__(16) u16 nr_hi[BM * LDA];
    __shared__ __align__(16) u16 nr_lo[BM * LDA];

    const u16* wcat_hi = ws + WCAT_HI;
    const u16* wcat_lo = ws + WCAT_LO;
    const u16* wc_hi   = ws + WC_HI;
    const u16* wc_lo   = ws + WC_LO;

    const int tid = threadIdx.x;
    const int w   = tid >> 6;          // wave 0..3
    const int l15 = tid & 15;
    const int lg  = (tid & 63) >> 4;   // lane group 0..3
    const int r0  = blockIdx.x * BM;

    // per-lane rank index for the middle phase (matches wave->N-tile map below)
    const int r = (w << 4) + l15;
    const float bdt_r  = b_dt[r];
    const float bph_r  = b_ph[r];
    const float expA_r = expf(A_real[r]);
    const float Aim_r  = A_imag[r];

    // stage-1 accumulators: g=0 dt, g=1 phase, g=2 B_val; m = M-tile (rows m*16..)
    f32x4 acc[3][2];
    #pragma unroll
    for (int g = 0; g < 3; ++g)
        #pragma unroll
        for (int m = 0; m < 2; ++m)
            acc[g][m] = (f32x4){0.f, 0.f, 0.f, 0.f};

    const int srow0 = tid >> 4;   // staging: thread covers f4 idx {tid, tid+256}
    const int sc4   = tid & 15;

    for (int it = 0; it < D_MODEL / KSTEP; ++it) {
        const int k0 = it * KSTEP;
        __syncthreads();   // protect LDS from previous iteration's readers
        #pragma unroll
        for (int v = 0; v < 2; ++v) {
            const int row = srow0 + v * 16;
            const f32x4 val = *(const f32x4*)(x + (size_t)(r0 + row) * D_MODEL + k0 + (sc4 << 2));
            u16x4 hi, lo;
            #pragma unroll
            for (int j = 0; j < 4; ++j) {
                hi[j] = f2bf(val[j]);
                lo[j] = f2bf(val[j] - bf2f(hi[j]));
            }
            *(u16x4*)(xa_hi + row * LDA + (sc4 << 2)) = hi;
            *(u16x4*)(xa_lo + row * LDA + (sc4 << 2)) = lo;
        }
        __syncthreads();
        #pragma unroll
        for (int kk = 0; kk < 2; ++kk) {
            bf16x8 ah[2], al[2];
            #pragma unroll
            for (int m = 0; m < 2; ++m) {
                const int off = (m * 16 + l15) * LDA + kk * 32 + lg * 8;
                ah[m] = *(const bf16x8*)(xa_hi + off);
                al[m] = *(const bf16x8*)(xa_lo + off);
            }
            const int kg = k0 + kk * 32 + lg * 8;
            #pragma unroll
            for (int g = 0; g < 3; ++g) {
                const int n = ((g << 2) + w) * 16 + l15;   // wave w -> N-tiles {w, w+4, w+8}
                const bf16x8 bh = *(const bf16x8*)(wcat_hi + n * 2048 + kg);
                const bf16x8 bl = *(const bf16x8*)(wcat_lo + n * 2048 + kg);
                #pragma unroll
                for (int m = 0; m < 2; ++m) {
                    acc[g][m] = MFMA(ah[m], bh, acc[g][m]);   // hi*hi
                    acc[g][m] = MFMA(al[m], bh, acc[g][m]);   // lo*hi
                    acc[g][m] = MFMA(ah[m], bl, acc[g][m]);   // hi*lo  (ll dropped, ~2^-18)
                }
            }
        }
    }

    // ---------------- middle: elementwise state update ----------------
    float* out_main = dout;
    float* out_nre  = dout + (size_t)BATCH * D_MODEL;
    float* out_nim  = out_nre + (size_t)BATCH * RANK;

    #pragma unroll
    for (int m = 0; m < 2; ++m) {
        #pragma unroll
        for (int j = 0; j < 4; ++j) {
            const int row_local = m * 16 + lg * 4 + j;   // D-frag: row=(l>>4)*4+j, col=l&15
            const size_t gb = (size_t)(r0 + row_local);
            const float ydt = acc[0][m][j] + bdt_r;
            const float dtv = fmaxf(ydt, 0.f) + log1pf(expf(-fabsf(ydt)));  // softplus
            const float yph = acc[1][m][j] + bph_r;
            const float ph  = tanhf(yph) * 3.14159274101257324f;
            const float bval = acc[2][m][j];
            const float decay = expf(-dtv * expA_r);
            const float angle = fmaf(dtv, Aim_r, ph);
            float sn, cs;
            sincosf(angle, &sn, &cs);
            const float sre = state_re[gb * RANK + r];
            const float sim = state_im[gb * RANK + r];
            const float nre = (sre * cs - sim * sn) * decay + bval;
            const float nim = (sre * sn + sim * cs) * decay;
            out_nre[gb * RANK + r] = nre;
            out_nim[gb * RANK + r] = nim;
            const u16 h = f2bf(nre);
            nr_hi[row_local * LDA + r] = h;
            nr_lo[row_local * LDA + r] = f2bf(nre - bf2f(h));
        }
    }
    __syncthreads();

    // ---------------- stage 2: out = new_re @ W_C^T ----------------
    bf16x8 ah2[2][2], al2[2][2];   // [m][kk] held in regs across all N-tiles
    #pragma unroll
    for (int m = 0; m < 2; ++m)
        #pragma unroll
        for (int kk = 0; kk < 2; ++kk) {
            const int off = (m * 16 + l15) * LDA + kk * 32 + lg * 8;
            ah2[m][kk] = *(const bf16x8*)(nr_hi + off);
            al2[m][kk] = *(const bf16x8*)(nr_lo + off);
        }

    const int dbase = w << 9;   // waves split N: 512 columns each
    for (int nt = 0; nt < 32; ++nt) {
        const int d = dbase + (nt << 4) + l15;
        bf16x8 bh[2], bl[2];
        #pragma unroll
        for (int kk = 0; kk < 2; ++kk) {
            const int off = (d << 6) + kk * 32 + lg * 8;
            bh[kk] = *(const bf16x8*)(wc_hi + off);
            bl[kk] = *(const bf16x8*)(wc_lo + off);
        }
        f32x4 acc2[2];
        #pragma unroll
        for (int m = 0; m < 2; ++m) {
            acc2[m] = (f32x4){0.f, 0.f, 0.f, 0.f};
            #pragma unroll
            for (int kk = 0; kk < 2; ++kk) {
                acc2[m] = MFMA(ah2[m][kk], bh[kk], acc2[m]);
                acc2[m] = MFMA(al2[m][kk], bh[kk], acc2[m]);
                acc2[m] = MFMA(ah2[m][kk], bl[kk], acc2[m]);
            }
        }
        #pragma unroll
        for (int m = 0; m < 2; ++m)
            #pragma unroll
            for (int j = 0; j < 4; ++j) {
                const int row_local = m * 16 + lg * 4 + j;
                out_main[(size_t)(r0 + row_local) * D_MODEL + d] = acc2[m][j];
            }
    }
}

extern "C" void kernel_launch(void* const* d_in, const int* in_sizes, int n_in,
                              void* d_out, int out_size, void* d_ws, size_t ws_size,
                              hipStream_t stream)
{
    const float* x        = (const float*)d_in[0];
    const float* state_re = (const float*)d_in[1];
    const float* state_im = (const float*)d_in[2];
    const float* W_dt     = (const float*)d_in[3];
    const float* b_dt     = (const float*)d_in[4];
    const float* W_ph     = (const float*)d_in[5];
    const float* b_ph     = (const float*)d_in[6];
    const float* W_B      = (const float*)d_in[7];
    const float* W_C      = (const float*)d_in[8];
    const float* A_real   = (const float*)d_in[9];
    const float* A_imag   = (const float*)d_in[10];
    u16*   ws  = (u16*)d_ws;     // needs 2 MiB
    float* out = (float*)d_out;

    prep_split<<<512, 256, 0, stream>>>(W_dt, W_ph, W_B, W_C, ws);
    mamba_fused<<<BATCH / BM, 256, 0, stream>>>(x, state_re, state_im, b_dt, b_ph,
                                                A_real, A_imag, ws, out);
}